// Round 1
// baseline (472.661 us; speedup 1.0000x reference)
//
#include <hip/hip_runtime.h>

#define NS 115            // contributing samples (S=116, last one unused)
#define WEPS 1e-5f
#define LOG_WEPS -11.5129254f

typedef float f32x4 __attribute__((ext_vector_type(4)));

struct SH9 { float a,b,c,d,e,f,g,h,i; };

__device__ __forceinline__ f32x4 load4(const float* p) {
    f32x4 v;
    __builtin_memcpy(&v, p, 16);
    return v;
}

__device__ __forceinline__ void pos_to_cell(float px, float py, float pz,
                                            int& ibase, float* wxs, float* wys, float* wzs) {
    px = fminf(fmaxf(px, 0.0f), 126.9999f);
    py = fminf(fmaxf(py, 0.0f), 126.9999f);
    pz = fminf(fmaxf(pz, 0.0f), 126.9999f);
    int ix = (int)px, iy = (int)py, iz = (int)pz;
    float wx = px - (float)ix, wy = py - (float)iy, wz = pz - (float)iz;
    ibase = (ix << 14) + (iy << 7) + iz;
    wxs[0] = 1.0f - wx; wxs[1] = wx;
    wys[0] = 1.0f - wy; wys[1] = wy;
    wzs[0] = 1.0f - wz; wzs[1] = wz;
}

// 8-corner trilerp of the opacity volume
__device__ __forceinline__ float eval_op(float px, float py, float pz,
                                         const float* __restrict__ opa) {
    int ibase; float wxs[2], wys[2], wzs[2];
    pos_to_cell(px, py, pz, ibase, wxs, wys, wzs);
    float op = 0.0f;
    #pragma unroll
    for (int cx = 0; cx < 2; ++cx)
    #pragma unroll
    for (int cy = 0; cy < 2; ++cy)
    #pragma unroll
    for (int cz = 0; cz < 2; ++cz) {
        int idx = ibase + (cx << 14) + (cy << 7) + cz;
        op = fmaf(wxs[cx] * wys[cy] * wzs[cz], opa[idx], op);
    }
    return fminf(fmaxf(op, 0.0f), 100000.0f);
}

// 8-corner trilerp of 27 SH coeffs folded with the SH dot (linear, so
// per-corner dot then weighted sum == interp then dot)
__device__ __forceinline__ void eval_color(float px, float py, float pz,
                                           const float* __restrict__ grid,
                                           const SH9& sh,
                                           float& cr, float& cg, float& cb) {
    int ibase; float wxs[2], wys[2], wzs[2];
    pos_to_cell(px, py, pz, ibase, wxs, wys, wzs);
    float r = 0.0f, g = 0.0f, b = 0.0f;
    #pragma unroll
    for (int cx = 0; cx < 2; ++cx)
    #pragma unroll
    for (int cy = 0; cy < 2; ++cy)
    #pragma unroll
    for (int cz = 0; cz < 2; ++cz) {
        int idx = ibase + (cx << 14) + (cy << 7) + cz;
        float wc = wxs[cx] * wys[cy] * wzs[cz];
        const float* cp = grid + (size_t)idx * 27;
        f32x4 v0 = load4(cp);
        f32x4 v1 = load4(cp + 4);
        f32x4 v2 = load4(cp + 8);
        f32x4 v3 = load4(cp + 12);
        f32x4 v4 = load4(cp + 16);
        f32x4 v5 = load4(cp + 20);
        f32x4 v6 = load4(cp + 23);   // covers elems 23,24,25,26 (23 dup)
        float c0 = sh.a*v0.x + sh.b*v0.y + sh.c*v0.z + sh.d*v0.w
                 + sh.e*v1.x + sh.f*v1.y + sh.g*v1.z + sh.h*v1.w + sh.i*v2.x;
        float c1 = sh.a*v2.y + sh.b*v2.z + sh.c*v2.w + sh.d*v3.x
                 + sh.e*v3.y + sh.f*v3.z + sh.g*v3.w + sh.h*v4.x + sh.i*v4.y;
        float c2 = sh.a*v4.z + sh.b*v4.w + sh.c*v5.x + sh.d*v5.y
                 + sh.e*v5.z + sh.f*v5.w + sh.g*v6.y + sh.h*v6.z + sh.i*v6.w;
        r = fmaf(wc, c0, r);
        g = fmaf(wc, c1, g);
        b = fmaf(wc, c2, b);
    }
    cr = fminf(fmaxf(r + 0.5f, 0.0f), 100000.0f);
    cg = fminf(fmaxf(g + 0.5f, 0.0f), 100000.0f);
    cb = fminf(fmaxf(b + 0.5f, 0.0f), 100000.0f);
}

__device__ __forceinline__ float wave_incl_scan(float v, int lane) {
    #pragma unroll
    for (int off = 1; off < 64; off <<= 1) {
        float n = __shfl_up(v, (unsigned)off, 64);
        if (lane >= off) v += n;
    }
    return v;
}

__global__ __launch_bounds__(256) void rf_kernel(
    const float* __restrict__ x, const float* __restrict__ d,
    const float* __restrict__ tmin, const float* __restrict__ tmax,
    const float* __restrict__ grid, const float* __restrict__ opa,
    float* __restrict__ out, int nrays)
{
    int gtid = blockIdx.x * blockDim.x + threadIdx.x;
    int ray = __builtin_amdgcn_readfirstlane(gtid >> 6);   // wave-uniform -> s_loads
    int lane = threadIdx.x & 63;
    if (ray >= nrays) return;

    float ox = x[3*ray+0], oy = x[3*ray+1], oz = x[3*ray+2];
    float ddx = d[3*ray+0], ddy = d[3*ray+1], ddz = d[3*ray+2];
    float t0 = tmin[ray], t1 = tmax[ray];
    float range = t1 - t0;
    float delta = range * 0.0078125f;      // (tmax-tmin)/128, constant per ray

    SH9 sh;
    sh.a = 0.28209479177387814f;
    sh.b = -0.4886025119029199f * ddy;
    sh.c =  0.4886025119029199f * ddz;
    sh.d = -0.4886025119029199f * ddx;
    sh.e =  1.0925484305920792f * ddx * ddy;
    sh.f = -1.0925484305920792f * ddy * ddz;
    sh.g =  0.31539156525252005f * (2.0f*ddz*ddz - ddx*ddx - ddy*ddy);
    sh.h = -1.0925484305920792f * ddx * ddz;
    sh.i =  0.5462742152960396f * (ddx*ddx - ddy*ddy);

    float accR = 0.0f, accG = 0.0f, accB = 0.0f;

    // ---- chunk 0: samples 0..63 (all lanes active) ----
    {
        int s = lane;
        float t = range * (0.05f + (float)s * 0.0078125f) + t0;
        float px = ox + t*ddx, py = oy + t*ddy, pz = oz + t*ddz;
        float opv = eval_op(px, py, pz, opa);
        float dts = -delta * opv;
        float incl = wave_incl_scan(dts, lane);
        float cum = incl - dts;                       // exclusive prefix
        float total0 = __shfl(incl, 63, 64);
        float w = __expf(cum) * (1.0f - __expf(dts));
        if (w > WEPS) {                                // suffix-sum bound <= WEPS
            float cr, cg, cb;
            eval_color(px, py, pz, grid, sh, cr, cg, cb);
            accR = w * cr; accG = w * cg; accB = w * cb;
        }
        // ---- chunk 1: samples 64..114, only if transmittance survives ----
        if (total0 > LOG_WEPS) {
            int s1 = 64 + lane;
            float dts1 = 0.0f;
            float px1 = 0.f, py1 = 0.f, pz1 = 0.f;
            if (s1 < NS) {
                float t1s = range * (0.05f + (float)s1 * 0.0078125f) + t0;
                px1 = ox + t1s*ddx; py1 = oy + t1s*ddy; pz1 = oz + t1s*ddz;
                float opv1 = eval_op(px1, py1, pz1, opa);
                dts1 = -delta * opv1;
            }
            float incl1 = wave_incl_scan(dts1, lane);
            float cum1 = total0 + incl1 - dts1;
            float w1 = __expf(cum1) * (1.0f - __expf(dts1));  // ==0 for s1>=NS
            if (w1 > WEPS) {
                float cr, cg, cb;
                eval_color(px1, py1, pz1, grid, sh, cr, cg, cb);
                accR = fmaf(w1, cr, accR);
                accG = fmaf(w1, cg, accG);
                accB = fmaf(w1, cb, accB);
            }
        }
    }

    // ---- wave reduction of RGB ----
    #pragma unroll
    for (int off = 32; off > 0; off >>= 1) {
        accR += __shfl_xor(accR, off, 64);
        accG += __shfl_xor(accG, off, 64);
        accB += __shfl_xor(accB, off, 64);
    }
    if (lane == 0) {
        out[3*ray+0] = accR;
        out[3*ray+1] = accG;
        out[3*ray+2] = accB;
    }
}

extern "C" void kernel_launch(void* const* d_in, const int* in_sizes, int n_in,
                              void* d_out, int out_size, void* d_ws, size_t ws_size,
                              hipStream_t stream) {
    const float* x    = (const float*)d_in[0];
    const float* d    = (const float*)d_in[1];
    const float* tmin = (const float*)d_in[2];
    const float* tmax = (const float*)d_in[3];
    const float* grid = (const float*)d_in[4];
    const float* opa  = (const float*)d_in[5];
    float* out = (float*)d_out;

    int nrays = in_sizes[0] / 3;                 // 32768
    int threads = 256;                           // 4 waves/block, 1 ray/wave
    int blocks = (nrays * 64 + threads - 1) / threads;   // 8192
    rf_kernel<<<blocks, threads, 0, stream>>>(x, d, tmin, tmax, grid, opa, out, nrays);
}

// Round 2
// 433.962 us; speedup vs baseline: 1.0892x; 1.0892x over previous
//
#include <hip/hip_runtime.h>

#define NS 115            // contributing samples (S=116, last one unused)
#define WEPS 5e-5f        // per-sample color skip (worst-case err 115*5e-5*~2 ~= 0.012 << 0.038)
#define LOG_TSKIP -6.9078f  // chunk1 skip when T < 1e-3 (err <= ~2e-3)

typedef float f32x4 __attribute__((ext_vector_type(4)));
typedef float f32x2 __attribute__((ext_vector_type(2)));

struct SH9 { float a,b,c,d,e,f,g,h,i; };

__device__ __forceinline__ f32x4 load4(const float* p) {
    f32x4 v;
    __builtin_memcpy(&v, p, 16);
    return v;
}
__device__ __forceinline__ f32x2 load2(const float* p) {
    f32x2 v;
    __builtin_memcpy(&v, p, 8);
    return v;
}

__device__ __forceinline__ void pos_to_cell(float px, float py, float pz,
                                            int& ibase, float* wxs, float* wys, float* wzs) {
    px = fminf(fmaxf(px, 0.0f), 126.9999f);
    py = fminf(fmaxf(py, 0.0f), 126.9999f);
    pz = fminf(fmaxf(pz, 0.0f), 126.9999f);
    int ix = (int)px, iy = (int)py, iz = (int)pz;
    float wx = px - (float)ix, wy = py - (float)iy, wz = pz - (float)iz;
    ibase = (ix << 14) + (iy << 7) + iz;
    wxs[0] = 1.0f - wx; wxs[1] = wx;
    wys[0] = 1.0f - wy; wys[1] = wy;
    wzs[0] = 1.0f - wz; wzs[1] = wz;
}

// 8-corner trilerp of the opacity volume; z-adjacent corners are contiguous
// in memory -> 4x dwordx2 gathers instead of 8 scalar gathers.
__device__ __forceinline__ float eval_op(float px, float py, float pz,
                                         const float* __restrict__ opa) {
    int ibase; float wxs[2], wys[2], wzs[2];
    pos_to_cell(px, py, pz, ibase, wxs, wys, wzs);
    float op = 0.0f;
    #pragma unroll
    for (int cx = 0; cx < 2; ++cx)
    #pragma unroll
    for (int cy = 0; cy < 2; ++cy) {
        int idx = ibase + (cx << 14) + (cy << 7);
        f32x2 pr = load2(opa + idx);          // corners (cz=0, cz=1)
        float wxy = wxs[cx] * wys[cy];
        op = fmaf(wxy * wzs[0], pr.x, op);
        op = fmaf(wxy * wzs[1], pr.y, op);
    }
    return fminf(fmaxf(op, 0.0f), 100000.0f);
}

// 8-corner trilerp of 27 SH coeffs folded with the SH dot (linear, so
// per-corner dot then weighted sum == interp then dot)
__device__ __forceinline__ void eval_color(float px, float py, float pz,
                                           const float* __restrict__ grid,
                                           const SH9& sh,
                                           float& cr, float& cg, float& cb) {
    int ibase; float wxs[2], wys[2], wzs[2];
    pos_to_cell(px, py, pz, ibase, wxs, wys, wzs);
    float r = 0.0f, g = 0.0f, b = 0.0f;
    #pragma unroll
    for (int cx = 0; cx < 2; ++cx)
    #pragma unroll
    for (int cy = 0; cy < 2; ++cy)
    #pragma unroll
    for (int cz = 0; cz < 2; ++cz) {
        int idx = ibase + (cx << 14) + (cy << 7) + cz;
        float wc = wxs[cx] * wys[cy] * wzs[cz];
        const float* cp = grid + (size_t)idx * 27;
        f32x4 v0 = load4(cp);
        f32x4 v1 = load4(cp + 4);
        f32x4 v2 = load4(cp + 8);
        f32x4 v3 = load4(cp + 12);
        f32x4 v4 = load4(cp + 16);
        f32x4 v5 = load4(cp + 20);
        f32x4 v6 = load4(cp + 23);   // covers elems 23,24,25,26 (23 dup)
        float c0 = sh.a*v0.x + sh.b*v0.y + sh.c*v0.z + sh.d*v0.w
                 + sh.e*v1.x + sh.f*v1.y + sh.g*v1.z + sh.h*v1.w + sh.i*v2.x;
        float c1 = sh.a*v2.y + sh.b*v2.z + sh.c*v2.w + sh.d*v3.x
                 + sh.e*v3.y + sh.f*v3.z + sh.g*v3.w + sh.h*v4.x + sh.i*v4.y;
        float c2 = sh.a*v4.z + sh.b*v4.w + sh.c*v5.x + sh.d*v5.y
                 + sh.e*v5.z + sh.f*v5.w + sh.g*v6.y + sh.h*v6.z + sh.i*v6.w;
        r = fmaf(wc, c0, r);
        g = fmaf(wc, c1, g);
        b = fmaf(wc, c2, b);
    }
    cr = fminf(fmaxf(r + 0.5f, 0.0f), 100000.0f);
    cg = fminf(fmaxf(g + 0.5f, 0.0f), 100000.0f);
    cb = fminf(fmaxf(b + 0.5f, 0.0f), 100000.0f);
}

__device__ __forceinline__ float wave_incl_scan(float v, int lane) {
    #pragma unroll
    for (int off = 1; off < 64; off <<= 1) {
        float n = __shfl_up(v, (unsigned)off, 64);
        if (lane >= off) v += n;
    }
    return v;
}

__global__ __launch_bounds__(256) void rf_kernel(
    const float* __restrict__ x, const float* __restrict__ d,
    const float* __restrict__ tmin, const float* __restrict__ tmax,
    const float* __restrict__ grid, const float* __restrict__ opa,
    float* __restrict__ out, int nrays)
{
    int gtid = blockIdx.x * blockDim.x + threadIdx.x;
    int ray = __builtin_amdgcn_readfirstlane(gtid >> 6);   // wave-uniform -> s_loads
    int lane = threadIdx.x & 63;
    if (ray >= nrays) return;

    float ox = x[3*ray+0], oy = x[3*ray+1], oz = x[3*ray+2];
    float ddx = d[3*ray+0], ddy = d[3*ray+1], ddz = d[3*ray+2];
    float t0 = tmin[ray], t1 = tmax[ray];
    float range = t1 - t0;
    float delta = range * 0.0078125f;      // (tmax-tmin)/128, constant per ray

    SH9 sh;
    sh.a = 0.28209479177387814f;
    sh.b = -0.4886025119029199f * ddy;
    sh.c =  0.4886025119029199f * ddz;
    sh.d = -0.4886025119029199f * ddx;
    sh.e =  1.0925484305920792f * ddx * ddy;
    sh.f = -1.0925484305920792f * ddy * ddz;
    sh.g =  0.31539156525252005f * (2.0f*ddz*ddz - ddx*ddx - ddy*ddy);
    sh.h = -1.0925484305920792f * ddx * ddz;
    sh.i =  0.5462742152960396f * (ddx*ddx - ddy*ddy);

    float accR = 0.0f, accG = 0.0f, accB = 0.0f;

    // ---- chunk 0: samples 0..63 (all lanes active) ----
    {
        int s = lane;
        float t = range * (0.05f + (float)s * 0.0078125f) + t0;
        float px = ox + t*ddx, py = oy + t*ddy, pz = oz + t*ddz;
        float opv = eval_op(px, py, pz, opa);
        float dts = -delta * opv;
        float incl = wave_incl_scan(dts, lane);
        float cum = incl - dts;                       // exclusive prefix
        float total0 = __shfl(incl, 63, 64);
        float w = __expf(cum) * (1.0f - __expf(dts));
        if (w > WEPS) {                                // skipped weights sum <= NS*WEPS
            float cr, cg, cb;
            eval_color(px, py, pz, grid, sh, cr, cg, cb);
            accR = w * cr; accG = w * cg; accB = w * cb;
        }
        // ---- chunk 1: samples 64..114, only if transmittance survives ----
        if (total0 > LOG_TSKIP) {
            int s1 = 64 + lane;
            float dts1 = 0.0f;
            float px1 = 0.f, py1 = 0.f, pz1 = 0.f;
            if (s1 < NS) {
                float t1s = range * (0.05f + (float)s1 * 0.0078125f) + t0;
                px1 = ox + t1s*ddx; py1 = oy + t1s*ddy; pz1 = oz + t1s*ddz;
                float opv1 = eval_op(px1, py1, pz1, opa);
                dts1 = -delta * opv1;
            }
            float incl1 = wave_incl_scan(dts1, lane);
            float cum1 = total0 + incl1 - dts1;
            float w1 = __expf(cum1) * (1.0f - __expf(dts1));  // ==0 for s1>=NS
            if (w1 > WEPS) {
                float cr, cg, cb;
                eval_color(px1, py1, pz1, grid, sh, cr, cg, cb);
                accR = fmaf(w1, cr, accR);
                accG = fmaf(w1, cg, accG);
                accB = fmaf(w1, cb, accB);
            }
        }
    }

    // ---- wave reduction of RGB ----
    #pragma unroll
    for (int off = 32; off > 0; off >>= 1) {
        accR += __shfl_xor(accR, off, 64);
        accG += __shfl_xor(accG, off, 64);
        accB += __shfl_xor(accB, off, 64);
    }
    if (lane == 0) {
        out[3*ray+0] = accR;
        out[3*ray+1] = accG;
        out[3*ray+2] = accB;
    }
}

extern "C" void kernel_launch(void* const* d_in, const int* in_sizes, int n_in,
                              void* d_out, int out_size, void* d_ws, size_t ws_size,
                              hipStream_t stream) {
    const float* x    = (const float*)d_in[0];
    const float* d    = (const float*)d_in[1];
    const float* tmin = (const float*)d_in[2];
    const float* tmax = (const float*)d_in[3];
    const float* grid = (const float*)d_in[4];
    const float* opa  = (const float*)d_in[5];
    float* out = (float*)d_out;

    int nrays = in_sizes[0] / 3;                 // 32768
    int threads = 256;                           // 4 waves/block, 1 ray/wave
    int blocks = (nrays * 64 + threads - 1) / threads;   // 8192
    rf_kernel<<<blocks, threads, 0, stream>>>(x, d, tmin, tmax, grid, opa, out, nrays);
}